// Round 1
// baseline (665.454 us; speedup 1.0000x reference)
//
#include <hip/hip_runtime.h>
#include <math.h>

// ---------------------------------------------------------------------------
// Graph prep kernels
// ---------------------------------------------------------------------------

__global__ __launch_bounds__(256)
void deg_kernel(const int* __restrict__ ei, const float* __restrict__ ew,
                int* __restrict__ cnt, float* __restrict__ sattr, int E)
{
    int e = blockIdx.x * 256 + threadIdx.x;
    if (e >= E) return;
    int d = ei[E + e];              // dst row of edge_index (2,E)
    atomicAdd(&cnt[d], 1);
    atomicAdd(&sattr[d], ew[e]);
}

// single-block exclusive scan of cnt -> row_off/cursor; also loop_attr = mean
__global__ __launch_bounds__(1024)
void scan_kernel(const int* __restrict__ cnt, const float* __restrict__ sattr,
                 int* __restrict__ row_off, int* __restrict__ cursor,
                 float* __restrict__ loop_attr, int n, int E)
{
    __shared__ int part[1024];
    const int tid = threadIdx.x;
    const int chunk = (n + 1023) / 1024;
    const int s  = tid * chunk;
    const int ee = min(s + chunk, n);
    int sum = 0;
    for (int i = s; i < ee; ++i) sum += cnt[i];
    part[tid] = sum;
    __syncthreads();
    for (int off = 1; off < 1024; off <<= 1) {   // Hillis-Steele inclusive
        int v = (tid >= off) ? part[tid - off] : 0;
        __syncthreads();
        part[tid] += v;
        __syncthreads();
    }
    int run = (tid == 0) ? 0 : part[tid - 1];
    for (int i = s; i < ee; ++i) {
        row_off[i] = run;
        cursor[i]  = run;
        int c = cnt[i];
        run += c;
        loop_attr[i] = sattr[i] / (float)max(c, 1);
    }
    if (tid == 0) row_off[n] = E;
}

__global__ __launch_bounds__(256)
void scatter_kernel(const int* __restrict__ ei, const float* __restrict__ ew,
                    int* __restrict__ cursor, int* __restrict__ slot_src,
                    float* __restrict__ slot_w, int E)
{
    int e = blockIdx.x * 256 + threadIdx.x;
    if (e >= E) return;
    int d = ei[E + e];
    int p = atomicAdd(&cursor[d], 1);
    slot_src[p] = ei[e];
    slot_w[p]   = ew[e];
}

// ---------------------------------------------------------------------------
// Fused linear: C[m][n] = sum_k X[m][k] * W[n][k] + bias[n]
// n < N/2 -> (Wa,ba) -> OutA ; else (Wb,bb) -> OutB. K, N fully LDS-resident.
// block = 256 threads, tile 64 rows x N cols, micro-tile 4 x (N/16).
// ---------------------------------------------------------------------------
template<int N, int K>
__global__ __launch_bounds__(256)
void gemm_xw(const float* __restrict__ X,
             const float* __restrict__ Wa, const float* __restrict__ Wb,
             const float* __restrict__ ba, const float* __restrict__ bb,
             float* __restrict__ OutA, float* __restrict__ OutB, int M)
{
    __shared__ float sA[64][K + 1];
    __shared__ float sB[N][K + 1];
    const int tid = threadIdx.x;
    const int m0  = blockIdx.x * 64;

    // load A tile (zero-fill past M)
    constexpr int KF4 = K / 4;
    for (int q = tid; q < 64 * KF4; q += 256) {
        int row = q / KF4;
        int c4  = (q % KF4) * 4;
        float4 v = make_float4(0.f, 0.f, 0.f, 0.f);
        int gr = m0 + row;
        if (gr < M) v = *(const float4*)(X + (size_t)gr * K + c4);
        sA[row][c4 + 0] = v.x; sA[row][c4 + 1] = v.y;
        sA[row][c4 + 2] = v.z; sA[row][c4 + 3] = v.w;
    }
    // load W (both halves)
    for (int q = tid; q < N * KF4; q += 256) {
        int nrow = q / KF4;
        int c4   = (q % KF4) * 4;
        const float* Wsrc = (nrow < N / 2) ? (Wa + (size_t)nrow * K)
                                           : (Wb + (size_t)(nrow - N / 2) * K);
        float4 v = *(const float4*)(Wsrc + c4);
        sB[nrow][c4 + 0] = v.x; sB[nrow][c4 + 1] = v.y;
        sB[nrow][c4 + 2] = v.z; sB[nrow][c4 + 3] = v.w;
    }
    __syncthreads();

    const int tr = tid >> 4;     // 0..15 -> rows tr*4 .. tr*4+3
    const int tc = tid & 15;     // 0..15 -> cols tc + 16*j
    constexpr int NJ = N / 16;
    float acc[4][NJ];
    #pragma unroll
    for (int i = 0; i < 4; ++i)
        #pragma unroll
        for (int j = 0; j < NJ; ++j) acc[i][j] = 0.f;

    for (int k = 0; k < K; ++k) {
        float a[4], b[NJ];
        #pragma unroll
        for (int i = 0; i < 4; ++i) a[i] = sA[tr * 4 + i][k];
        #pragma unroll
        for (int j = 0; j < NJ; ++j) b[j] = sB[tc + 16 * j][k];
        #pragma unroll
        for (int i = 0; i < 4; ++i)
            #pragma unroll
            for (int j = 0; j < NJ; ++j) acc[i][j] += a[i] * b[j];
    }

    #pragma unroll
    for (int i = 0; i < 4; ++i) {
        int row = m0 + tr * 4 + i;
        if (row >= M) continue;
        #pragma unroll
        for (int j = 0; j < NJ; ++j) {
            int nn = tc + 16 * j;
            if (nn < N / 2) {
                OutA[(size_t)row * (N / 2) + nn] = acc[i][j] + ba[nn];
            } else {
                OutB[(size_t)row * (N / 2) + nn - N / 2] = acc[i][j] + bb[nn - N / 2];
            }
        }
    }
}

// ---------------------------------------------------------------------------
// Per-node GATv2 attention + aggregation. One (sub-)wave of D lanes per node.
// Single pass: no segment-max needed (scores are O(10), exp fits fp32 easily;
// softmax is shift-invariant so result identical).
// ACT: 0 = ELU (layer 1), 1 = softplus + 1e-4 (layer 2)
// ---------------------------------------------------------------------------
template<int D, int ACT>
__global__ __launch_bounds__(256)
void edge_attn(const float* __restrict__ xl, const float* __restrict__ xr,
               const float* __restrict__ We, const float* __restrict__ att,
               const float* __restrict__ bias, const float* __restrict__ loop_attr,
               const int* __restrict__ row_off, const int* __restrict__ slot_src,
               const float* __restrict__ slot_w, float* __restrict__ out, int n)
{
    constexpr int NP = 64 / D;                 // nodes per wave
    const int lane = threadIdx.x & 63;
    const int wid  = threadIdx.x >> 6;         // wave in block (4 waves)
    const int sub  = lane / D;
    const int h    = lane % D;
    const int node = (blockIdx.x * 4 + wid) * NP + sub;
    if (node >= n) return;

    const float We_h   = We[h];
    const float att_h  = att[h];
    const float bias_h = bias[h];
    const float xr_h   = xr[(size_t)node * D + h];

    const int start = row_off[node];
    const int end   = row_off[node + 1];

    float denom = 0.f, acc = 0.f;
    for (int j = start; j <= end; ++j) {       // j == end -> self-loop
        int src; float w;
        if (j < end) { src = slot_src[j]; w = slot_w[j]; }
        else         { src = node;        w = loop_attr[node]; }
        float xlv = xl[(size_t)src * D + h];
        float v = xlv + xr_h + w * We_h;
        float m = v > 0.f ? v : 0.2f * v;      // leaky_relu(0.2)
        float p = att_h * m;
        #pragma unroll
        for (int mask = D / 2; mask >= 1; mask >>= 1)
            p += __shfl_xor(p, mask);          // score broadcast to all D lanes
        float e = __expf(p);
        denom += e;
        acc   += e * xlv;
    }
    float res = acc / denom + bias_h;
    if (ACT == 0) {
        res = res > 0.f ? res : expm1f(res);                       // ELU
    } else {
        res = fmaxf(res, 0.f) + log1pf(expf(-fabsf(res))) + 1e-4f; // softplus + eps
    }
    out[(size_t)node * D + h] = res;
}

// ---------------------------------------------------------------------------
extern "C" void kernel_launch(void* const* d_in, const int* in_sizes, int n_in,
                              void* d_out, int out_size, void* d_ws, size_t ws_size,
                              hipStream_t stream)
{
    const float* x     = (const float*)d_in[0];
    const int*   ei    = (const int*)d_in[1];     // (2, E) int32
    const float* ew    = (const float*)d_in[2];
    const float* Wl1   = (const float*)d_in[3];
    const float* bl1   = (const float*)d_in[4];
    const float* Wr1   = (const float*)d_in[5];
    const float* br1   = (const float*)d_in[6];
    const float* We1   = (const float*)d_in[7];
    const float* att1  = (const float*)d_in[8];
    const float* bias1 = (const float*)d_in[9];
    const float* Wl2   = (const float*)d_in[10];
    const float* bl2   = (const float*)d_in[11];
    const float* Wr2   = (const float*)d_in[12];
    const float* br2   = (const float*)d_in[13];
    const float* We2   = (const float*)d_in[14];
    const float* att2  = (const float*)d_in[15];
    const float* bias2 = (const float*)d_in[16];
    float* out = (float*)d_out;

    const int n = in_sizes[0] / 128;
    const int E = in_sizes[2];

    // workspace carve (256B aligned)
    char* wp = (char*)d_ws;
    auto carve = [&](size_t bytes) -> void* {
        void* p = (void*)wp;
        wp += (bytes + 255) & ~(size_t)255;
        return p;
    };
    int*   cnt       = (int*)  carve((size_t)n * 4);
    float* sattr     = (float*)carve((size_t)n * 4);
    int*   row_off   = (int*)  carve((size_t)(n + 1) * 4);
    int*   cursor    = (int*)  carve((size_t)n * 4);
    float* loop_attr = (float*)carve((size_t)n * 4);
    int*   slot_src  = (int*)  carve((size_t)E * 4);
    float* slot_w    = (float*)carve((size_t)E * 4);
    float* xl1       = (float*)carve((size_t)n * 64 * 4);
    float* xr1       = (float*)carve((size_t)n * 64 * 4);
    float* hbuf      = (float*)carve((size_t)n * 64 * 4);
    float* xl2       = (float*)carve((size_t)n * 32 * 4);
    float* xr2       = (float*)carve((size_t)n * 32 * 4);

    // zero the two accumulated arrays (contiguous carve: cnt then sattr)
    hipMemsetAsync(cnt, 0, ((size_t)n * 4 + 255 & ~(size_t)255) + (size_t)n * 4, stream);

    deg_kernel   <<<(E + 255) / 256, 256, 0, stream>>>(ei, ew, cnt, sattr, E);
    scan_kernel  <<<1, 1024, 0, stream>>>(cnt, sattr, row_off, cursor, loop_attr, n, E);
    scatter_kernel<<<(E + 255) / 256, 256, 0, stream>>>(ei, ew, cursor, slot_src, slot_w, E);

    // layer 1
    gemm_xw<128, 128><<<(n + 63) / 64, 256, 0, stream>>>(x, Wl1, Wr1, bl1, br1, xl1, xr1, n);
    edge_attn<64, 0><<<(n + 3) / 4, 256, 0, stream>>>(xl1, xr1, We1, att1, bias1, loop_attr,
                                                      row_off, slot_src, slot_w, hbuf, n);
    // layer 2
    gemm_xw<64, 64><<<(n + 63) / 64, 256, 0, stream>>>(hbuf, Wl2, Wr2, bl2, br2, xl2, xr2, n);
    edge_attn<32, 1><<<(n + 7) / 8, 256, 0, stream>>>(xl2, xr2, We2, att2, bias2, loop_attr,
                                                      row_off, slot_src, slot_w, out, n);
}

// Round 2
// 482.218 us; speedup vs baseline: 1.3800x; 1.3800x over previous
//
#include <hip/hip_runtime.h>
#include <math.h>

// ---------------------------------------------------------------------------
// Graph prep kernels
// ---------------------------------------------------------------------------

__global__ __launch_bounds__(256)
void deg_kernel(const int* __restrict__ ei, const float* __restrict__ ew,
                int* __restrict__ cnt, float* __restrict__ sattr, int E)
{
    int e = blockIdx.x * 256 + threadIdx.x;
    if (e >= E) return;
    int d = ei[E + e];              // dst row of edge_index (2,E)
    atomicAdd(&cnt[d], 1);
    atomicAdd(&sattr[d], ew[e]);
}

// --- 3-phase multi-block exclusive scan of cnt (n=50K -> 196 blocks) -------
__global__ __launch_bounds__(256)
void scan_p1(const int* __restrict__ cnt, int* __restrict__ bsums, int n)
{
    __shared__ int s[256];
    const int tid = threadIdx.x;
    int gi = blockIdx.x * 256 + tid;
    s[tid] = (gi < n) ? cnt[gi] : 0;
    __syncthreads();
    #pragma unroll
    for (int off = 128; off >= 1; off >>= 1) {
        if (tid < off) s[tid] += s[tid + off];
        __syncthreads();
    }
    if (tid == 0) bsums[blockIdx.x] = s[0];
}

// single block; nb <= 256 (n fixed at 50K -> nb = 196)
__global__ __launch_bounds__(256)
void scan_p2(int* __restrict__ bsums, int nb)
{
    __shared__ int s[256];
    const int tid = threadIdx.x;
    int v = (tid < nb) ? bsums[tid] : 0;
    s[tid] = v;
    __syncthreads();
    #pragma unroll
    for (int off = 1; off < 256; off <<= 1) {   // Hillis-Steele inclusive
        int t = (tid >= off) ? s[tid - off] : 0;
        __syncthreads();
        s[tid] += t;
        __syncthreads();
    }
    if (tid < nb) bsums[tid] = s[tid] - v;      // exclusive
}

__global__ __launch_bounds__(256)
void scan_p3(const int* __restrict__ cnt, const float* __restrict__ sattr,
             const int* __restrict__ bsums, int* __restrict__ row_off,
             int* __restrict__ cursor, float* __restrict__ loop_attr, int n)
{
    __shared__ int s[256];
    const int tid = threadIdx.x;
    int gi = blockIdx.x * 256 + tid;
    int c = (gi < n) ? cnt[gi] : 0;
    s[tid] = c;
    __syncthreads();
    #pragma unroll
    for (int off = 1; off < 256; off <<= 1) {   // inclusive scan of the tile
        int t = (tid >= off) ? s[tid - off] : 0;
        __syncthreads();
        s[tid] += t;
        __syncthreads();
    }
    if (gi < n) {
        int excl = bsums[blockIdx.x] + s[tid] - c;
        row_off[gi] = excl;
        cursor[gi]  = excl;
        loop_attr[gi] = sattr[gi] / (float)max(c, 1);
        if (gi == n - 1) row_off[n] = excl + c;   // == E
    }
}

__global__ __launch_bounds__(256)
void scatter_kernel(const int* __restrict__ ei, const float* __restrict__ ew,
                    int* __restrict__ cursor, int* __restrict__ slot_src,
                    float* __restrict__ slot_w, int E)
{
    int e = blockIdx.x * 256 + threadIdx.x;
    if (e >= E) return;
    int d = ei[E + e];
    int p = atomicAdd(&cursor[d], 1);
    slot_src[p] = ei[e];
    slot_w[p]   = ew[e];
}

// ---------------------------------------------------------------------------
// Fused linear: C[m][n] = sum_k X[m][k] * W[n][k] + bias[n]
// n < N/2 -> (Wa,ba) -> OutA ; else (Wb,bb) -> OutB. K, N fully LDS-resident.
// block = 256 threads, tile 64 rows x N cols, micro-tile 4 x (N/16).
// ---------------------------------------------------------------------------
template<int N, int K>
__global__ __launch_bounds__(256)
void gemm_xw(const float* __restrict__ X,
             const float* __restrict__ Wa, const float* __restrict__ Wb,
             const float* __restrict__ ba, const float* __restrict__ bb,
             float* __restrict__ OutA, float* __restrict__ OutB, int M)
{
    __shared__ float sA[64][K + 1];
    __shared__ float sB[N][K + 1];
    const int tid = threadIdx.x;
    const int m0  = blockIdx.x * 64;

    constexpr int KF4 = K / 4;
    for (int q = tid; q < 64 * KF4; q += 256) {
        int row = q / KF4;
        int c4  = (q % KF4) * 4;
        float4 v = make_float4(0.f, 0.f, 0.f, 0.f);
        int gr = m0 + row;
        if (gr < M) v = *(const float4*)(X + (size_t)gr * K + c4);
        sA[row][c4 + 0] = v.x; sA[row][c4 + 1] = v.y;
        sA[row][c4 + 2] = v.z; sA[row][c4 + 3] = v.w;
    }
    for (int q = tid; q < N * KF4; q += 256) {
        int nrow = q / KF4;
        int c4   = (q % KF4) * 4;
        const float* Wsrc = (nrow < N / 2) ? (Wa + (size_t)nrow * K)
                                           : (Wb + (size_t)(nrow - N / 2) * K);
        float4 v = *(const float4*)(Wsrc + c4);
        sB[nrow][c4 + 0] = v.x; sB[nrow][c4 + 1] = v.y;
        sB[nrow][c4 + 2] = v.z; sB[nrow][c4 + 3] = v.w;
    }
    __syncthreads();

    const int tr = tid >> 4;
    const int tc = tid & 15;
    constexpr int NJ = N / 16;
    float acc[4][NJ];
    #pragma unroll
    for (int i = 0; i < 4; ++i)
        #pragma unroll
        for (int j = 0; j < NJ; ++j) acc[i][j] = 0.f;

    for (int k = 0; k < K; ++k) {
        float a[4], b[NJ];
        #pragma unroll
        for (int i = 0; i < 4; ++i) a[i] = sA[tr * 4 + i][k];
        #pragma unroll
        for (int j = 0; j < NJ; ++j) b[j] = sB[tc + 16 * j][k];
        #pragma unroll
        for (int i = 0; i < 4; ++i)
            #pragma unroll
            for (int j = 0; j < NJ; ++j) acc[i][j] += a[i] * b[j];
    }

    #pragma unroll
    for (int i = 0; i < 4; ++i) {
        int row = m0 + tr * 4 + i;
        if (row >= M) continue;
        #pragma unroll
        for (int j = 0; j < NJ; ++j) {
            int nn = tc + 16 * j;
            if (nn < N / 2) {
                OutA[(size_t)row * (N / 2) + nn] = acc[i][j] + ba[nn];
            } else {
                OutB[(size_t)row * (N / 2) + nn - N / 2] = acc[i][j] + bb[nn - N / 2];
            }
        }
    }
}

// ---------------------------------------------------------------------------
// Per-node GATv2 attention + aggregation. One (sub-)wave of D lanes per node.
// Single pass: no segment-max needed (scores are O(10), exp fits fp32 easily;
// softmax is shift-invariant so result identical).
// ACT: 0 = ELU (layer 1), 1 = softplus + 1e-4 (layer 2)
// ---------------------------------------------------------------------------
template<int D, int ACT>
__global__ __launch_bounds__(256)
void edge_attn(const float* __restrict__ xl, const float* __restrict__ xr,
               const float* __restrict__ We, const float* __restrict__ att,
               const float* __restrict__ bias, const float* __restrict__ loop_attr,
               const int* __restrict__ row_off, const int* __restrict__ slot_src,
               const float* __restrict__ slot_w, float* __restrict__ out, int n)
{
    constexpr int NP = 64 / D;                 // nodes per wave
    const int lane = threadIdx.x & 63;
    const int wid  = threadIdx.x >> 6;         // wave in block (4 waves)
    const int sub  = lane / D;
    const int h    = lane % D;
    const int node = (blockIdx.x * 4 + wid) * NP + sub;
    if (node >= n) return;

    const float We_h   = We[h];
    const float att_h  = att[h];
    const float bias_h = bias[h];
    const float xr_h   = xr[(size_t)node * D + h];

    const int start = row_off[node];
    const int end   = row_off[node + 1];

    float denom = 0.f, acc = 0.f;
    for (int j = start; j <= end; ++j) {       // j == end -> self-loop
        int src; float w;
        if (j < end) { src = slot_src[j]; w = slot_w[j]; }
        else         { src = node;        w = loop_attr[node]; }
        float xlv = xl[(size_t)src * D + h];
        float v = xlv + xr_h + w * We_h;
        float m = v > 0.f ? v : 0.2f * v;      // leaky_relu(0.2)
        float p = att_h * m;
        #pragma unroll
        for (int mask = D / 2; mask >= 1; mask >>= 1)
            p += __shfl_xor(p, mask);          // score broadcast to all D lanes
        float e = __expf(p);
        denom += e;
        acc   += e * xlv;
    }
    float res = acc / denom + bias_h;
    if (ACT == 0) {
        res = res > 0.f ? res : expm1f(res);                       // ELU
    } else {
        res = fmaxf(res, 0.f) + log1pf(expf(-fabsf(res))) + 1e-4f; // softplus + eps
    }
    out[(size_t)node * D + h] = res;
}

// ---------------------------------------------------------------------------
extern "C" void kernel_launch(void* const* d_in, const int* in_sizes, int n_in,
                              void* d_out, int out_size, void* d_ws, size_t ws_size,
                              hipStream_t stream)
{
    const float* x     = (const float*)d_in[0];
    const int*   ei    = (const int*)d_in[1];     // (2, E) int32
    const float* ew    = (const float*)d_in[2];
    const float* Wl1   = (const float*)d_in[3];
    const float* bl1   = (const float*)d_in[4];
    const float* Wr1   = (const float*)d_in[5];
    const float* br1   = (const float*)d_in[6];
    const float* We1   = (const float*)d_in[7];
    const float* att1  = (const float*)d_in[8];
    const float* bias1 = (const float*)d_in[9];
    const float* Wl2   = (const float*)d_in[10];
    const float* bl2   = (const float*)d_in[11];
    const float* Wr2   = (const float*)d_in[12];
    const float* br2   = (const float*)d_in[13];
    const float* We2   = (const float*)d_in[14];
    const float* att2  = (const float*)d_in[15];
    const float* bias2 = (const float*)d_in[16];
    float* out = (float*)d_out;

    const int n = in_sizes[0] / 128;
    const int E = in_sizes[2];
    const int NB = (n + 255) / 256;               // 196 scan blocks (<= 256)

    // workspace carve (256B aligned)
    char* wp = (char*)d_ws;
    auto carve = [&](size_t bytes) -> void* {
        void* p = (void*)wp;
        wp += (bytes + 255) & ~(size_t)255;
        return p;
    };
    int*   cnt       = (int*)  carve((size_t)n * 4);
    float* sattr     = (float*)carve((size_t)n * 4);
    int*   row_off   = (int*)  carve((size_t)(n + 1) * 4);
    int*   cursor    = (int*)  carve((size_t)n * 4);
    float* loop_attr = (float*)carve((size_t)n * 4);
    int*   bsums     = (int*)  carve((size_t)256 * 4);
    int*   slot_src  = (int*)  carve((size_t)E * 4);
    float* slot_w    = (float*)carve((size_t)E * 4);
    float* xl1       = (float*)carve((size_t)n * 64 * 4);
    float* xr1       = (float*)carve((size_t)n * 64 * 4);
    float* hbuf      = (float*)carve((size_t)n * 64 * 4);
    float* xl2       = (float*)carve((size_t)n * 32 * 4);
    float* xr2       = (float*)carve((size_t)n * 32 * 4);

    // zero the two accumulated arrays (contiguous carve: cnt then sattr)
    hipMemsetAsync(cnt, 0, (((size_t)n * 4 + 255) & ~(size_t)255) + (size_t)n * 4, stream);

    deg_kernel    <<<(E + 255) / 256, 256, 0, stream>>>(ei, ew, cnt, sattr, E);
    scan_p1       <<<NB, 256, 0, stream>>>(cnt, bsums, n);
    scan_p2       <<<1, 256, 0, stream>>>(bsums, NB);
    scan_p3       <<<NB, 256, 0, stream>>>(cnt, sattr, bsums, row_off, cursor, loop_attr, n);
    scatter_kernel<<<(E + 255) / 256, 256, 0, stream>>>(ei, ew, cursor, slot_src, slot_w, E);

    // layer 1
    gemm_xw<128, 128><<<(n + 63) / 64, 256, 0, stream>>>(x, Wl1, Wr1, bl1, br1, xl1, xr1, n);
    edge_attn<64, 0><<<(n + 3) / 4, 256, 0, stream>>>(xl1, xr1, We1, att1, bias1, loop_attr,
                                                      row_off, slot_src, slot_w, hbuf, n);
    // layer 2
    gemm_xw<64, 64><<<(n + 63) / 64, 256, 0, stream>>>(hbuf, Wl2, Wr2, bl2, br2, xl2, xr2, n);
    edge_attn<32, 1><<<(n + 7) / 8, 256, 0, stream>>>(xl2, xr2, We2, att2, bias2, loop_attr,
                                                      row_off, slot_src, slot_w, out, n);
}

// Round 3
// 402.012 us; speedup vs baseline: 1.6553x; 1.1995x over previous
//
#include <hip/hip_runtime.h>
#include <math.h>

// ---------------------------------------------------------------------------
// Graph prep kernels
// ---------------------------------------------------------------------------

__global__ __launch_bounds__(256)
void deg_kernel(const int* __restrict__ ei, const float* __restrict__ ew,
                int* __restrict__ cnt, float* __restrict__ sattr, int E)
{
    int e = blockIdx.x * 256 + threadIdx.x;
    if (e >= E) return;
    int d = ei[E + e];              // dst row of edge_index (2,E)
    atomicAdd(&cnt[d], 1);
    atomicAdd(&sattr[d], ew[e]);
}

// --- 3-phase multi-block exclusive scan of cnt (n=50K -> 196 blocks) -------
__global__ __launch_bounds__(256)
void scan_p1(const int* __restrict__ cnt, int* __restrict__ bsums, int n)
{
    __shared__ int s[256];
    const int tid = threadIdx.x;
    int gi = blockIdx.x * 256 + tid;
    s[tid] = (gi < n) ? cnt[gi] : 0;
    __syncthreads();
    #pragma unroll
    for (int off = 128; off >= 1; off >>= 1) {
        if (tid < off) s[tid] += s[tid + off];
        __syncthreads();
    }
    if (tid == 0) bsums[blockIdx.x] = s[0];
}

// single block; nb <= 256 (n fixed at 50K -> nb = 196)
__global__ __launch_bounds__(256)
void scan_p2(int* __restrict__ bsums, int nb)
{
    __shared__ int s[256];
    const int tid = threadIdx.x;
    int v = (tid < nb) ? bsums[tid] : 0;
    s[tid] = v;
    __syncthreads();
    #pragma unroll
    for (int off = 1; off < 256; off <<= 1) {   // Hillis-Steele inclusive
        int t = (tid >= off) ? s[tid - off] : 0;
        __syncthreads();
        s[tid] += t;
        __syncthreads();
    }
    if (tid < nb) bsums[tid] = s[tid] - v;      // exclusive
}

__global__ __launch_bounds__(256)
void scan_p3(const int* __restrict__ cnt, const float* __restrict__ sattr,
             const int* __restrict__ bsums, int* __restrict__ row_off,
             int* __restrict__ cursor, float* __restrict__ loop_attr, int n)
{
    __shared__ int s[256];
    const int tid = threadIdx.x;
    int gi = blockIdx.x * 256 + tid;
    int c = (gi < n) ? cnt[gi] : 0;
    s[tid] = c;
    __syncthreads();
    #pragma unroll
    for (int off = 1; off < 256; off <<= 1) {   // inclusive scan of the tile
        int t = (tid >= off) ? s[tid - off] : 0;
        __syncthreads();
        s[tid] += t;
        __syncthreads();
    }
    if (gi < n) {
        int excl = bsums[blockIdx.x] + s[tid] - c;
        row_off[gi] = excl;
        cursor[gi]  = excl;
        loop_attr[gi] = sattr[gi] / (float)max(c, 1);
        if (gi == n - 1) row_off[n] = excl + c;   // == E
    }
}

// writes (src, weight_bits) pairs so edge_attn does ONE 8B load per edge
__global__ __launch_bounds__(256)
void scatter_kernel(const int* __restrict__ ei, const float* __restrict__ ew,
                    int* __restrict__ cursor, int2* __restrict__ slot, int E)
{
    int e = blockIdx.x * 256 + threadIdx.x;
    if (e >= E) return;
    int d = ei[E + e];
    int p = atomicAdd(&cursor[d], 1);
    slot[p] = make_int2(ei[e], __float_as_int(ew[e]));
}

// ---------------------------------------------------------------------------
// Fused linear: C[m][n] = sum_k X[m][k] * W[n][k] + bias[n]
// n < N/2 -> (Wa,ba) -> OutA ; else (Wb,bb) -> OutB. K, N fully LDS-resident.
// block = 256 threads, tile 64 rows x N cols, micro-tile 4 x (N/16).
// ---------------------------------------------------------------------------
template<int N, int K>
__global__ __launch_bounds__(256)
void gemm_xw(const float* __restrict__ X,
             const float* __restrict__ Wa, const float* __restrict__ Wb,
             const float* __restrict__ ba, const float* __restrict__ bb,
             float* __restrict__ OutA, float* __restrict__ OutB, int M)
{
    __shared__ float sA[64][K + 1];
    __shared__ float sB[N][K + 1];
    const int tid = threadIdx.x;
    const int m0  = blockIdx.x * 64;

    constexpr int KF4 = K / 4;
    for (int q = tid; q < 64 * KF4; q += 256) {
        int row = q / KF4;
        int c4  = (q % KF4) * 4;
        float4 v = make_float4(0.f, 0.f, 0.f, 0.f);
        int gr = m0 + row;
        if (gr < M) v = *(const float4*)(X + (size_t)gr * K + c4);
        sA[row][c4 + 0] = v.x; sA[row][c4 + 1] = v.y;
        sA[row][c4 + 2] = v.z; sA[row][c4 + 3] = v.w;
    }
    for (int q = tid; q < N * KF4; q += 256) {
        int nrow = q / KF4;
        int c4   = (q % KF4) * 4;
        const float* Wsrc = (nrow < N / 2) ? (Wa + (size_t)nrow * K)
                                           : (Wb + (size_t)(nrow - N / 2) * K);
        float4 v = *(const float4*)(Wsrc + c4);
        sB[nrow][c4 + 0] = v.x; sB[nrow][c4 + 1] = v.y;
        sB[nrow][c4 + 2] = v.z; sB[nrow][c4 + 3] = v.w;
    }
    __syncthreads();

    const int tr = tid >> 4;
    const int tc = tid & 15;
    constexpr int NJ = N / 16;
    float acc[4][NJ];
    #pragma unroll
    for (int i = 0; i < 4; ++i)
        #pragma unroll
        for (int j = 0; j < NJ; ++j) acc[i][j] = 0.f;

    for (int k = 0; k < K; ++k) {
        float a[4], b[NJ];
        #pragma unroll
        for (int i = 0; i < 4; ++i) a[i] = sA[tr * 4 + i][k];
        #pragma unroll
        for (int j = 0; j < NJ; ++j) b[j] = sB[tc + 16 * j][k];
        #pragma unroll
        for (int i = 0; i < 4; ++i)
            #pragma unroll
            for (int j = 0; j < NJ; ++j) acc[i][j] += a[i] * b[j];
    }

    #pragma unroll
    for (int i = 0; i < 4; ++i) {
        int row = m0 + tr * 4 + i;
        if (row >= M) continue;
        #pragma unroll
        for (int j = 0; j < NJ; ++j) {
            int nn = tc + 16 * j;
            if (nn < N / 2) {
                OutA[(size_t)row * (N / 2) + nn] = acc[i][j] + ba[nn];
            } else {
                OutB[(size_t)row * (N / 2) + nn - N / 2] = acc[i][j] + bb[nn - N / 2];
            }
        }
    }
}

// ---------------------------------------------------------------------------
// Per-node GATv2 attention + aggregation. One (sub-)wave of D lanes per node.
// Edge loop unrolled x4: 4 gathers in flight + 4 interleaved shuffle chains
// to hide the ~300-cycle L2/L3 gather latency (round-2 profile: VALUBusy 40%,
// HBM 12% -> latency-bound).
// ACT: 0 = ELU (layer 1), 1 = softplus + 1e-4 (layer 2)
// ---------------------------------------------------------------------------
template<int D, int ACT>
__global__ __launch_bounds__(256)
void edge_attn(const float* __restrict__ xl, const float* __restrict__ xr,
               const float* __restrict__ We, const float* __restrict__ att,
               const float* __restrict__ bias, const float* __restrict__ loop_attr,
               const int* __restrict__ row_off, const int2* __restrict__ slot,
               float* __restrict__ out, int n)
{
    constexpr int NP = 64 / D;                 // nodes per wave
    const int lane = threadIdx.x & 63;
    const int wid  = threadIdx.x >> 6;         // wave in block (4 waves)
    const int sub  = lane / D;
    const int h    = lane % D;
    const int node = (blockIdx.x * 4 + wid) * NP + sub;
    if (node >= n) return;

    const float We_h   = We[h];
    const float att_h  = att[h];
    const float bias_h = bias[h];
    const float xr_h   = xr[(size_t)node * D + h];

    const int start = row_off[node];
    const int end   = row_off[node + 1];

    float denom = 0.f, acc = 0.f;
    int j = start;
    for (; j + 4 <= end; j += 4) {
        int2 q0 = slot[j + 0];
        int2 q1 = slot[j + 1];
        int2 q2 = slot[j + 2];
        int2 q3 = slot[j + 3];
        float xv0 = xl[(size_t)q0.x * D + h];
        float xv1 = xl[(size_t)q1.x * D + h];
        float xv2 = xl[(size_t)q2.x * D + h];
        float xv3 = xl[(size_t)q3.x * D + h];
        float v0 = xv0 + xr_h + __int_as_float(q0.y) * We_h;
        float v1 = xv1 + xr_h + __int_as_float(q1.y) * We_h;
        float v2 = xv2 + xr_h + __int_as_float(q2.y) * We_h;
        float v3 = xv3 + xr_h + __int_as_float(q3.y) * We_h;
        float p0 = att_h * (v0 > 0.f ? v0 : 0.2f * v0);
        float p1 = att_h * (v1 > 0.f ? v1 : 0.2f * v1);
        float p2 = att_h * (v2 > 0.f ? v2 : 0.2f * v2);
        float p3 = att_h * (v3 > 0.f ? v3 : 0.2f * v3);
        #pragma unroll
        for (int mask = D / 2; mask >= 1; mask >>= 1) {
            p0 += __shfl_xor(p0, mask);
            p1 += __shfl_xor(p1, mask);
            p2 += __shfl_xor(p2, mask);
            p3 += __shfl_xor(p3, mask);
        }
        float e0 = __expf(p0);
        float e1 = __expf(p1);
        float e2 = __expf(p2);
        float e3 = __expf(p3);
        denom += (e0 + e1) + (e2 + e3);
        acc   += (e0 * xv0 + e1 * xv1) + (e2 * xv2 + e3 * xv3);
    }
    for (; j <= end; ++j) {                    // tail + self-loop (j == end)
        int src; float w;
        if (j < end) { int2 q = slot[j]; src = q.x; w = __int_as_float(q.y); }
        else         { src = node;       w = loop_attr[node]; }
        float xlv = xl[(size_t)src * D + h];
        float v = xlv + xr_h + w * We_h;
        float p = att_h * (v > 0.f ? v : 0.2f * v);
        #pragma unroll
        for (int mask = D / 2; mask >= 1; mask >>= 1)
            p += __shfl_xor(p, mask);
        float e = __expf(p);
        denom += e;
        acc   += e * xlv;
    }
    float res = acc / denom + bias_h;
    if (ACT == 0) {
        res = res > 0.f ? res : expm1f(res);                       // ELU
    } else {
        res = fmaxf(res, 0.f) + log1pf(expf(-fabsf(res))) + 1e-4f; // softplus + eps
    }
    out[(size_t)node * D + h] = res;
}

// ---------------------------------------------------------------------------
extern "C" void kernel_launch(void* const* d_in, const int* in_sizes, int n_in,
                              void* d_out, int out_size, void* d_ws, size_t ws_size,
                              hipStream_t stream)
{
    const float* x     = (const float*)d_in[0];
    const int*   ei    = (const int*)d_in[1];     // (2, E) int32
    const float* ew    = (const float*)d_in[2];
    const float* Wl1   = (const float*)d_in[3];
    const float* bl1   = (const float*)d_in[4];
    const float* Wr1   = (const float*)d_in[5];
    const float* br1   = (const float*)d_in[6];
    const float* We1   = (const float*)d_in[7];
    const float* att1  = (const float*)d_in[8];
    const float* bias1 = (const float*)d_in[9];
    const float* Wl2   = (const float*)d_in[10];
    const float* bl2   = (const float*)d_in[11];
    const float* Wr2   = (const float*)d_in[12];
    const float* br2   = (const float*)d_in[13];
    const float* We2   = (const float*)d_in[14];
    const float* att2  = (const float*)d_in[15];
    const float* bias2 = (const float*)d_in[16];
    float* out = (float*)d_out;

    const int n = in_sizes[0] / 128;
    const int E = in_sizes[2];
    const int NB = (n + 255) / 256;               // 196 scan blocks (<= 256)

    // workspace carve (256B aligned)
    char* wp = (char*)d_ws;
    auto carve = [&](size_t bytes) -> void* {
        void* p = (void*)wp;
        wp += (bytes + 255) & ~(size_t)255;
        return p;
    };
    int*   cnt       = (int*)  carve((size_t)n * 4);
    float* sattr     = (float*)carve((size_t)n * 4);
    int*   row_off   = (int*)  carve((size_t)(n + 1) * 4);
    int*   cursor    = (int*)  carve((size_t)n * 4);
    float* loop_attr = (float*)carve((size_t)n * 4);
    int*   bsums     = (int*)  carve((size_t)256 * 4);
    int2*  slot      = (int2*) carve((size_t)E * 8);
    float* xl1       = (float*)carve((size_t)n * 64 * 4);
    float* xr1       = (float*)carve((size_t)n * 64 * 4);
    float* hbuf      = (float*)carve((size_t)n * 64 * 4);
    float* xl2       = (float*)carve((size_t)n * 32 * 4);
    float* xr2       = (float*)carve((size_t)n * 32 * 4);

    // zero the two accumulated arrays (contiguous carve: cnt then sattr)
    hipMemsetAsync(cnt, 0, (((size_t)n * 4 + 255) & ~(size_t)255) + (size_t)n * 4, stream);

    deg_kernel    <<<(E + 255) / 256, 256, 0, stream>>>(ei, ew, cnt, sattr, E);
    scan_p1       <<<NB, 256, 0, stream>>>(cnt, bsums, n);
    scan_p2       <<<1, 256, 0, stream>>>(bsums, NB);
    scan_p3       <<<NB, 256, 0, stream>>>(cnt, sattr, bsums, row_off, cursor, loop_attr, n);
    scatter_kernel<<<(E + 255) / 256, 256, 0, stream>>>(ei, ew, cursor, slot, E);

    // layer 1
    gemm_xw<128, 128><<<(n + 63) / 64, 256, 0, stream>>>(x, Wl1, Wr1, bl1, br1, xl1, xr1, n);
    edge_attn<64, 0><<<(n + 3) / 4, 256, 0, stream>>>(xl1, xr1, We1, att1, bias1, loop_attr,
                                                      row_off, slot, hbuf, n);
    // layer 2
    gemm_xw<64, 64><<<(n + 63) / 64, 256, 0, stream>>>(hbuf, Wl2, Wr2, bl2, br2, xl2, xr2, n);
    edge_attn<32, 1><<<(n + 7) / 8, 256, 0, stream>>>(xl2, xr2, We2, att2, bias2, loop_attr,
                                                      row_off, slot, out, n);
}

// Round 4
// 335.728 us; speedup vs baseline: 1.9821x; 1.1974x over previous
//
#include <hip/hip_runtime.h>
#include <math.h>

// ---------------------------------------------------------------------------
// Graph prep kernels
// ---------------------------------------------------------------------------

// count in-degree only (self-loop attr mean is computed inside edge_attn now)
__global__ __launch_bounds__(256)
void deg_kernel(const int* __restrict__ ei, int* __restrict__ cnt, int E)
{
    int e = blockIdx.x * 256 + threadIdx.x;
    if (e >= E) return;
    atomicAdd(&cnt[ei[E + e]], 1);
}

// --- 3-phase multi-block exclusive scan of cnt (n=50K -> 196 blocks) -------
__global__ __launch_bounds__(256)
void scan_p1(const int* __restrict__ cnt, int* __restrict__ bsums, int n)
{
    __shared__ int s[256];
    const int tid = threadIdx.x;
    int gi = blockIdx.x * 256 + tid;
    s[tid] = (gi < n) ? cnt[gi] : 0;
    __syncthreads();
    #pragma unroll
    for (int off = 128; off >= 1; off >>= 1) {
        if (tid < off) s[tid] += s[tid + off];
        __syncthreads();
    }
    if (tid == 0) bsums[blockIdx.x] = s[0];
}

__global__ __launch_bounds__(256)
void scan_p2(int* __restrict__ bsums, int nb)
{
    __shared__ int s[256];
    const int tid = threadIdx.x;
    int v = (tid < nb) ? bsums[tid] : 0;
    s[tid] = v;
    __syncthreads();
    #pragma unroll
    for (int off = 1; off < 256; off <<= 1) {
        int t = (tid >= off) ? s[tid - off] : 0;
        __syncthreads();
        s[tid] += t;
        __syncthreads();
    }
    if (tid < nb) bsums[tid] = s[tid] - v;      // exclusive
}

__global__ __launch_bounds__(256)
void scan_p3(const int* __restrict__ cnt, const int* __restrict__ bsums,
             int* __restrict__ row_off, int* __restrict__ cursor, int n)
{
    __shared__ int s[256];
    const int tid = threadIdx.x;
    int gi = blockIdx.x * 256 + tid;
    int c = (gi < n) ? cnt[gi] : 0;
    s[tid] = c;
    __syncthreads();
    #pragma unroll
    for (int off = 1; off < 256; off <<= 1) {
        int t = (tid >= off) ? s[tid - off] : 0;
        __syncthreads();
        s[tid] += t;
        __syncthreads();
    }
    if (gi < n) {
        int excl = bsums[blockIdx.x] + s[tid] - c;
        row_off[gi] = excl;
        cursor[gi]  = excl;
        if (gi == n - 1) row_off[n] = excl + c;   // == E
    }
}

// writes (src, weight_bits) pairs so edge_attn does ONE 8B load per edge
__global__ __launch_bounds__(256)
void scatter_kernel(const int* __restrict__ ei, const float* __restrict__ ew,
                    int* __restrict__ cursor, int2* __restrict__ slot, int E)
{
    int e = blockIdx.x * 256 + threadIdx.x;
    if (e >= E) return;
    int d = ei[E + e];
    int p = atomicAdd(&cursor[d], 1);
    slot[p] = make_int2(ei[e], __float_as_int(ew[e]));
}

// ---------------------------------------------------------------------------
// Fused linear: C[m][col] = sum_k X[m][k] * W[col][k] + bias[col]
// col < N/2 -> (Wa,ba) -> OutA ; else (Wb,bb) -> OutB.
// Tile: M=128 rows x N cols, K in chunks of 32. 256 threads, 8 x (N/16)
// micro-tile, rows/cols interleaved by 16 so simultaneous lanes hit distinct
// XOR-swizzled LDS quads (conflict-free float4 reads; pad-free 32KB LDS ->
// 2-3 blocks/CU vs round-3's 1).
// swizzle: element (r, k=kq*4+c) at  r*32 + ((kq ^ (r&7))<<2) + c
// ---------------------------------------------------------------------------
template<int N, int K>
__global__ __launch_bounds__(256, 2)
void gemm_xw(const float* __restrict__ X,
             const float* __restrict__ Wa, const float* __restrict__ Wb,
             const float* __restrict__ ba, const float* __restrict__ bb,
             float* __restrict__ OutA, float* __restrict__ OutB, int M)
{
    constexpr int NJ = N / 16;                  // cols per thread
    __shared__ float sA[128 * 32];
    __shared__ float sB[N * 32];
    const int tid = threadIdx.x;
    const int m0  = blockIdx.x * 128;
    const int rg  = tid >> 4;                   // 0..15, rows rg + 16*i
    const int cg  = tid & 15;                   // 0..15, cols cg + 16*j

    float acc[8][NJ];
    #pragma unroll
    for (int i = 0; i < 8; ++i)
        #pragma unroll
        for (int j = 0; j < NJ; ++j) acc[i][j] = 0.f;

    const int sr = tid >> 3;                    // staging row within pass
    const int kq = tid & 7;                     // staging quad
    const int aswz = (kq ^ (sr & 7)) << 2;

    for (int kb = 0; kb < K; kb += 32) {
        // stage A: 128 rows x 32 floats (4 passes of 32 rows)
        #pragma unroll
        for (int p = 0; p < 4; ++p) {
            int r = sr + 32 * p;
            float4 v = make_float4(0.f, 0.f, 0.f, 0.f);
            int gr = m0 + r;
            if (gr < M) v = *(const float4*)(X + (size_t)gr * K + kb + kq * 4);
            *(float4*)&sA[r * 32 + aswz] = v;
        }
        // stage B: N rows x 32 floats
        #pragma unroll
        for (int p = 0; p < N / 32; ++p) {
            int r = sr + 32 * p;
            const float* Wsrc = (r < N / 2) ? (Wa + (size_t)r * K)
                                            : (Wb + (size_t)(r - N / 2) * K);
            float4 v = *(const float4*)(Wsrc + kb + kq * 4);
            *(float4*)&sB[r * 32 + aswz] = v;
        }
        __syncthreads();

        #pragma unroll
        for (int q = 0; q < 8; ++q) {
            float4 a4[8], b4[NJ];
            const int sa_off = (q ^ (rg & 7)) << 2;
            const int sb_off = (q ^ (cg & 7)) << 2;
            #pragma unroll
            for (int i = 0; i < 8; ++i)
                a4[i] = *(const float4*)&sA[(rg + 16 * i) * 32 + sa_off];
            #pragma unroll
            for (int j = 0; j < NJ; ++j)
                b4[j] = *(const float4*)&sB[(cg + 16 * j) * 32 + sb_off];
            #pragma unroll
            for (int i = 0; i < 8; ++i)
                #pragma unroll
                for (int j = 0; j < NJ; ++j) {
                    acc[i][j] += a4[i].x * b4[j].x;
                    acc[i][j] += a4[i].y * b4[j].y;
                    acc[i][j] += a4[i].z * b4[j].z;
                    acc[i][j] += a4[i].w * b4[j].w;
                }
        }
        __syncthreads();
    }

    #pragma unroll
    for (int i = 0; i < 8; ++i) {
        int row = m0 + rg + 16 * i;
        if (row >= M) continue;
        #pragma unroll
        for (int j = 0; j < NJ; ++j) {
            int col = cg + 16 * j;
            if (col < N / 2) {
                OutA[(size_t)row * (N / 2) + col] = acc[i][j] + ba[col];
            } else {
                OutB[(size_t)row * (N / 2) + col - N / 2] = acc[i][j] + bb[col - N / 2];
            }
        }
    }
}

// ---------------------------------------------------------------------------
// Per-node GATv2 attention + aggregation. One (sub-)wave of D lanes per node.
// Edge loop unrolled x4 (4 gathers in flight). Self-loop weight = mean of
// incoming edge weights, accumulated in-loop (wsum) -- no loop_attr buffer.
// ACT: 0 = ELU (layer 1), 1 = softplus + 1e-4 (layer 2)
// ---------------------------------------------------------------------------
template<int D, int ACT>
__global__ __launch_bounds__(256)
void edge_attn(const float* __restrict__ xl, const float* __restrict__ xr,
               const float* __restrict__ We, const float* __restrict__ att,
               const float* __restrict__ bias,
               const int* __restrict__ row_off, const int2* __restrict__ slot,
               float* __restrict__ out, int n)
{
    constexpr int NP = 64 / D;                 // nodes per wave
    const int lane = threadIdx.x & 63;
    const int wid  = threadIdx.x >> 6;         // wave in block (4 waves)
    const int sub  = lane / D;
    const int h    = lane % D;
    const int node = (blockIdx.x * 4 + wid) * NP + sub;
    if (node >= n) return;

    const float We_h   = We[h];
    const float att_h  = att[h];
    const float bias_h = bias[h];
    const float xr_h   = xr[(size_t)node * D + h];

    const int start = row_off[node];
    const int end   = row_off[node + 1];

    float denom = 0.f, acc = 0.f, wsum = 0.f;
    int j = start;
    for (; j + 4 <= end; j += 4) {
        int2 q0 = slot[j + 0];
        int2 q1 = slot[j + 1];
        int2 q2 = slot[j + 2];
        int2 q3 = slot[j + 3];
        float xv0 = xl[(size_t)q0.x * D + h];
        float xv1 = xl[(size_t)q1.x * D + h];
        float xv2 = xl[(size_t)q2.x * D + h];
        float xv3 = xl[(size_t)q3.x * D + h];
        float w0 = __int_as_float(q0.y);
        float w1 = __int_as_float(q1.y);
        float w2 = __int_as_float(q2.y);
        float w3 = __int_as_float(q3.y);
        wsum += (w0 + w1) + (w2 + w3);
        float v0 = xv0 + xr_h + w0 * We_h;
        float v1 = xv1 + xr_h + w1 * We_h;
        float v2 = xv2 + xr_h + w2 * We_h;
        float v3 = xv3 + xr_h + w3 * We_h;
        float p0 = att_h * (v0 > 0.f ? v0 : 0.2f * v0);
        float p1 = att_h * (v1 > 0.f ? v1 : 0.2f * v1);
        float p2 = att_h * (v2 > 0.f ? v2 : 0.2f * v2);
        float p3 = att_h * (v3 > 0.f ? v3 : 0.2f * v3);
        #pragma unroll
        for (int mask = D / 2; mask >= 1; mask >>= 1) {
            p0 += __shfl_xor(p0, mask);
            p1 += __shfl_xor(p1, mask);
            p2 += __shfl_xor(p2, mask);
            p3 += __shfl_xor(p3, mask);
        }
        float e0 = __expf(p0);
        float e1 = __expf(p1);
        float e2 = __expf(p2);
        float e3 = __expf(p3);
        denom += (e0 + e1) + (e2 + e3);
        acc   += (e0 * xv0 + e1 * xv1) + (e2 * xv2 + e3 * xv3);
    }
    for (; j < end; ++j) {                     // tail
        int2 q = slot[j];
        float w = __int_as_float(q.y);
        wsum += w;
        float xlv = xl[(size_t)q.x * D + h];
        float v = xlv + xr_h + w * We_h;
        float p = att_h * (v > 0.f ? v : 0.2f * v);
        #pragma unroll
        for (int mask = D / 2; mask >= 1; mask >>= 1)
            p += __shfl_xor(p, mask);
        float e = __expf(p);
        denom += e;
        acc   += e * xlv;
    }
    {   // self-loop: w = mean of incoming edge weights
        float w = wsum / (float)max(end - start, 1);
        float xlv = xl[(size_t)node * D + h];
        float v = xlv + xr_h + w * We_h;
        float p = att_h * (v > 0.f ? v : 0.2f * v);
        #pragma unroll
        for (int mask = D / 2; mask >= 1; mask >>= 1)
            p += __shfl_xor(p, mask);
        float e = __expf(p);
        denom += e;
        acc   += e * xlv;
    }
    float res = acc / denom + bias_h;
    if (ACT == 0) {
        res = res > 0.f ? res : expm1f(res);                       // ELU
    } else {
        res = fmaxf(res, 0.f) + log1pf(expf(-fabsf(res))) + 1e-4f; // softplus + eps
    }
    out[(size_t)node * D + h] = res;
}

// ---------------------------------------------------------------------------
extern "C" void kernel_launch(void* const* d_in, const int* in_sizes, int n_in,
                              void* d_out, int out_size, void* d_ws, size_t ws_size,
                              hipStream_t stream)
{
    const float* x     = (const float*)d_in[0];
    const int*   ei    = (const int*)d_in[1];     // (2, E) int32
    const float* ew    = (const float*)d_in[2];
    const float* Wl1   = (const float*)d_in[3];
    const float* bl1   = (const float*)d_in[4];
    const float* Wr1   = (const float*)d_in[5];
    const float* br1   = (const float*)d_in[6];
    const float* We1   = (const float*)d_in[7];
    const float* att1  = (const float*)d_in[8];
    const float* bias1 = (const float*)d_in[9];
    const float* Wl2   = (const float*)d_in[10];
    const float* bl2   = (const float*)d_in[11];
    const float* Wr2   = (const float*)d_in[12];
    const float* br2   = (const float*)d_in[13];
    const float* We2   = (const float*)d_in[14];
    const float* att2  = (const float*)d_in[15];
    const float* bias2 = (const float*)d_in[16];
    float* out = (float*)d_out;

    const int n = in_sizes[0] / 128;
    const int E = in_sizes[2];
    const int NB = (n + 255) / 256;               // 196 scan blocks (<= 256)

    // workspace carve (256B aligned)
    char* wp = (char*)d_ws;
    auto carve = [&](size_t bytes) -> void* {
        void* p = (void*)wp;
        wp += (bytes + 255) & ~(size_t)255;
        return p;
    };
    int*   cnt       = (int*)  carve((size_t)n * 4);
    int*   row_off   = (int*)  carve((size_t)(n + 1) * 4);
    int*   cursor    = (int*)  carve((size_t)n * 4);
    int*   bsums     = (int*)  carve((size_t)256 * 4);
    int2*  slot      = (int2*) carve((size_t)E * 8);
    float* xl1       = (float*)carve((size_t)n * 64 * 4);
    float* xr1       = (float*)carve((size_t)n * 64 * 4);
    float* hbuf      = (float*)carve((size_t)n * 64 * 4);
    float* xl2       = (float*)carve((size_t)n * 32 * 4);
    float* xr2       = (float*)carve((size_t)n * 32 * 4);

    hipMemsetAsync(cnt, 0, (size_t)n * 4, stream);

    deg_kernel    <<<(E + 255) / 256, 256, 0, stream>>>(ei, cnt, E);
    scan_p1       <<<NB, 256, 0, stream>>>(cnt, bsums, n);
    scan_p2       <<<1, 256, 0, stream>>>(bsums, NB);
    scan_p3       <<<NB, 256, 0, stream>>>(cnt, bsums, row_off, cursor, n);
    scatter_kernel<<<(E + 255) / 256, 256, 0, stream>>>(ei, ew, cursor, slot, E);

    // layer 1
    gemm_xw<128, 128><<<(n + 127) / 128, 256, 0, stream>>>(x, Wl1, Wr1, bl1, br1, xl1, xr1, n);
    edge_attn<64, 0><<<(n + 3) / 4, 256, 0, stream>>>(xl1, xr1, We1, att1, bias1,
                                                      row_off, slot, hbuf, n);
    // layer 2
    gemm_xw<64, 64><<<(n + 127) / 128, 256, 0, stream>>>(hbuf, Wl2, Wr2, bl2, br2, xl2, xr2, n);
    edge_attn<32, 1><<<(n + 7) / 8, 256, 0, stream>>>(xl2, xr2, We2, att2, bias2,
                                                      row_off, slot, out, n);
}

// Round 5
// 333.891 us; speedup vs baseline: 1.9930x; 1.0055x over previous
//
#include <hip/hip_runtime.h>
#include <math.h>

// ---------------------------------------------------------------------------
// Graph prep kernels
// ---------------------------------------------------------------------------

// count in-degree only (self-loop attr mean is computed inside edge_attn)
__global__ __launch_bounds__(256)
void deg_kernel(const int* __restrict__ ei, int* __restrict__ cnt, int E)
{
    int e = blockIdx.x * 256 + threadIdx.x;
    if (e >= E) return;
    atomicAdd(&cnt[ei[E + e]], 1);
}

// --- 3-phase multi-block exclusive scan of cnt (n=50K -> 196 blocks) -------
__global__ __launch_bounds__(256)
void scan_p1(const int* __restrict__ cnt, int* __restrict__ bsums, int n)
{
    __shared__ int s[256];
    const int tid = threadIdx.x;
    int gi = blockIdx.x * 256 + tid;
    s[tid] = (gi < n) ? cnt[gi] : 0;
    __syncthreads();
    #pragma unroll
    for (int off = 128; off >= 1; off >>= 1) {
        if (tid < off) s[tid] += s[tid + off];
        __syncthreads();
    }
    if (tid == 0) bsums[blockIdx.x] = s[0];
}

__global__ __launch_bounds__(256)
void scan_p2(int* __restrict__ bsums, int nb)
{
    __shared__ int s[256];
    const int tid = threadIdx.x;
    int v = (tid < nb) ? bsums[tid] : 0;
    s[tid] = v;
    __syncthreads();
    #pragma unroll
    for (int off = 1; off < 256; off <<= 1) {
        int t = (tid >= off) ? s[tid - off] : 0;
        __syncthreads();
        s[tid] += t;
        __syncthreads();
    }
    if (tid < nb) bsums[tid] = s[tid] - v;      // exclusive
}

__global__ __launch_bounds__(256)
void scan_p3(const int* __restrict__ cnt, const int* __restrict__ bsums,
             int* __restrict__ row_off, int* __restrict__ cursor, int n)
{
    __shared__ int s[256];
    const int tid = threadIdx.x;
    int gi = blockIdx.x * 256 + tid;
    int c = (gi < n) ? cnt[gi] : 0;
    s[tid] = c;
    __syncthreads();
    #pragma unroll
    for (int off = 1; off < 256; off <<= 1) {
        int t = (tid >= off) ? s[tid - off] : 0;
        __syncthreads();
        s[tid] += t;
        __syncthreads();
    }
    if (gi < n) {
        int excl = bsums[blockIdx.x] + s[tid] - c;
        row_off[gi] = excl;
        cursor[gi]  = excl;
        if (gi == n - 1) row_off[n] = excl + c;   // == E
    }
}

// writes (src, weight_bits) pairs so edge_attn does ONE 8B load per edge
__global__ __launch_bounds__(256)
void scatter_kernel(const int* __restrict__ ei, const float* __restrict__ ew,
                    int* __restrict__ cursor, int2* __restrict__ slot, int E)
{
    int e = blockIdx.x * 256 + threadIdx.x;
    if (e >= E) return;
    int d = ei[E + e];
    int p = atomicAdd(&cursor[d], 1);
    slot[p] = make_int2(ei[e], __float_as_int(ew[e]));
}

// ---------------------------------------------------------------------------
// Fused linear: C[m][col] = sum_k X[m][k] * W[col][k] + bias[col]
// (unchanged from round 4: XOR-quad-swizzled LDS, 128x128 tile, K chunks 32)
// ---------------------------------------------------------------------------
template<int N, int K>
__global__ __launch_bounds__(256, 2)
void gemm_xw(const float* __restrict__ X,
             const float* __restrict__ Wa, const float* __restrict__ Wb,
             const float* __restrict__ ba, const float* __restrict__ bb,
             float* __restrict__ OutA, float* __restrict__ OutB, int M)
{
    constexpr int NJ = N / 16;
    __shared__ float sA[128 * 32];
    __shared__ float sB[N * 32];
    const int tid = threadIdx.x;
    const int m0  = blockIdx.x * 128;
    const int rg  = tid >> 4;
    const int cg  = tid & 15;

    float acc[8][NJ];
    #pragma unroll
    for (int i = 0; i < 8; ++i)
        #pragma unroll
        for (int j = 0; j < NJ; ++j) acc[i][j] = 0.f;

    const int sr = tid >> 3;
    const int kq = tid & 7;
    const int aswz = (kq ^ (sr & 7)) << 2;

    for (int kb = 0; kb < K; kb += 32) {
        #pragma unroll
        for (int p = 0; p < 4; ++p) {
            int r = sr + 32 * p;
            float4 v = make_float4(0.f, 0.f, 0.f, 0.f);
            int gr = m0 + r;
            if (gr < M) v = *(const float4*)(X + (size_t)gr * K + kb + kq * 4);
            *(float4*)&sA[r * 32 + aswz] = v;
        }
        #pragma unroll
        for (int p = 0; p < N / 32; ++p) {
            int r = sr + 32 * p;
            const float* Wsrc = (r < N / 2) ? (Wa + (size_t)r * K)
                                            : (Wb + (size_t)(r - N / 2) * K);
            float4 v = *(const float4*)(Wsrc + kb + kq * 4);
            *(float4*)&sB[r * 32 + aswz] = v;
        }
        __syncthreads();

        #pragma unroll
        for (int q = 0; q < 8; ++q) {
            float4 a4[8], b4[NJ];
            const int sa_off = (q ^ (rg & 7)) << 2;
            const int sb_off = (q ^ (cg & 7)) << 2;
            #pragma unroll
            for (int i = 0; i < 8; ++i)
                a4[i] = *(const float4*)&sA[(rg + 16 * i) * 32 + sa_off];
            #pragma unroll
            for (int j = 0; j < NJ; ++j)
                b4[j] = *(const float4*)&sB[(cg + 16 * j) * 32 + sb_off];
            #pragma unroll
            for (int i = 0; i < 8; ++i)
                #pragma unroll
                for (int j = 0; j < NJ; ++j) {
                    acc[i][j] += a4[i].x * b4[j].x;
                    acc[i][j] += a4[i].y * b4[j].y;
                    acc[i][j] += a4[i].z * b4[j].z;
                    acc[i][j] += a4[i].w * b4[j].w;
                }
        }
        __syncthreads();
    }

    #pragma unroll
    for (int i = 0; i < 8; ++i) {
        int row = m0 + rg + 16 * i;
        if (row >= M) continue;
        #pragma unroll
        for (int j = 0; j < NJ; ++j) {
            int col = cg + 16 * j;
            if (col < N / 2) {
                OutA[(size_t)row * (N / 2) + col] = acc[i][j] + ba[col];
            } else {
                OutB[(size_t)row * (N / 2) + col - N / 2] = acc[i][j] + bb[col - N / 2];
            }
        }
    }
}

// ---------------------------------------------------------------------------
// Per-node GATv2 attention + aggregation, float4-per-lane layout.
// LPE = D/4 lanes per edge; SG = 64/LPE edges processed per wave-round.
// One wave per node. Gather is global_load_dwordx4 (16B/lane); the score
// butterfly is log2(LPE) steps shared by SG edges. Tail = one predicated
// round. Self-loop (w = mean incoming weight) after cross-subgroup combine.
// ACT: 0 = ELU (layer 1), 1 = softplus + 1e-4 (layer 2)
// ---------------------------------------------------------------------------
template<int D, int ACT>
__global__ __launch_bounds__(256)
void edge_attn(const float* __restrict__ xl, const float* __restrict__ xr,
               const float* __restrict__ We, const float* __restrict__ att,
               const float* __restrict__ bias,
               const int* __restrict__ row_off, const int2* __restrict__ slot,
               float* __restrict__ out, int n)
{
    constexpr int LPE = D / 4;                 // lanes per edge
    constexpr int SG  = 64 / LPE;              // edges per round
    const int lane = threadIdx.x & 63;
    const int wid  = threadIdx.x >> 6;
    const int t    = lane % LPE;               // owns dims 4t..4t+3
    const int g    = lane / LPE;               // edge slot within round
    const int node = blockIdx.x * 4 + wid;
    if (node >= n) return;

    const float4 We4   = *(const float4*)(We   + 4 * t);
    const float4 att4  = *(const float4*)(att  + 4 * t);
    const float4 bias4 = *(const float4*)(bias + 4 * t);
    const float4 xr4   = *(const float4*)(xr + (size_t)node * D + 4 * t);

    const int start = row_off[node];
    const int end   = row_off[node + 1];

    float denom = 0.f, wsum = 0.f;
    float4 acc = make_float4(0.f, 0.f, 0.f, 0.f);

    auto body = [&](int2 q, float4 xv, bool active) {
        float w = __int_as_float(q.y);
        float4 v;
        v.x = xv.x + xr4.x + w * We4.x;
        v.y = xv.y + xr4.y + w * We4.y;
        v.z = xv.z + xr4.z + w * We4.z;
        v.w = xv.w + xr4.w + w * We4.w;
        // leaky_relu(0.2): max(v, 0.2v) (equal for both signs' winner)
        float4 m;
        m.x = fmaxf(v.x, 0.2f * v.x);
        m.y = fmaxf(v.y, 0.2f * v.y);
        m.z = fmaxf(v.z, 0.2f * v.z);
        m.w = fmaxf(v.w, 0.2f * v.w);
        float p = att4.x * m.x + att4.y * m.y + att4.z * m.z + att4.w * m.w;
        #pragma unroll
        for (int mask = LPE / 2; mask >= 1; mask >>= 1)
            p += __shfl_xor(p, mask);          // score for this edge, LPE lanes
        float e = active ? __expf(p) : 0.f;
        wsum  += active ? w : 0.f;
        denom += e;
        acc.x += e * xv.x;
        acc.y += e * xv.y;
        acc.z += e * xv.z;
        acc.w += e * xv.w;
    };

    int j = start;
    for (; j + 2 * SG <= end; j += 2 * SG) {   // 2 rounds in flight
        int2 qa = slot[j + g];
        int2 qb = slot[j + SG + g];
        float4 xa = *(const float4*)(xl + (size_t)qa.x * D + 4 * t);
        float4 xb = *(const float4*)(xl + (size_t)qb.x * D + 4 * t);
        body(qa, xa, true);
        body(qb, xb, true);
    }
    for (; j + SG <= end; j += SG) {
        int2 q = slot[j + g];
        float4 xv = *(const float4*)(xl + (size_t)q.x * D + 4 * t);
        body(q, xv, true);
    }
    if (j < end) {                             // predicated tail round
        int idx = min(j + g, end - 1);
        int2 q = slot[idx];
        float4 xv = *(const float4*)(xl + (size_t)q.x * D + 4 * t);
        body(q, xv, (j + g) < end);
    }

    // combine partials across the SG subgroups
    #pragma unroll
    for (int mask = LPE; mask < 64; mask <<= 1) {
        denom += __shfl_xor(denom, mask);
        wsum  += __shfl_xor(wsum,  mask);
        acc.x += __shfl_xor(acc.x, mask);
        acc.y += __shfl_xor(acc.y, mask);
        acc.z += __shfl_xor(acc.z, mask);
        acc.w += __shfl_xor(acc.w, mask);
    }

    {   // self-loop: w = mean of incoming edge weights
        float w = wsum / (float)max(end - start, 1);
        float4 xv = *(const float4*)(xl + (size_t)node * D + 4 * t);
        float4 v;
        v.x = xv.x + xr4.x + w * We4.x;
        v.y = xv.y + xr4.y + w * We4.y;
        v.z = xv.z + xr4.z + w * We4.z;
        v.w = xv.w + xr4.w + w * We4.w;
        float4 m;
        m.x = fmaxf(v.x, 0.2f * v.x);
        m.y = fmaxf(v.y, 0.2f * v.y);
        m.z = fmaxf(v.z, 0.2f * v.z);
        m.w = fmaxf(v.w, 0.2f * v.w);
        float p = att4.x * m.x + att4.y * m.y + att4.z * m.z + att4.w * m.w;
        #pragma unroll
        for (int mask = LPE / 2; mask >= 1; mask >>= 1)
            p += __shfl_xor(p, mask);
        float e = __expf(p);
        denom += e;
        acc.x += e * xv.x;
        acc.y += e * xv.y;
        acc.z += e * xv.z;
        acc.w += e * xv.w;
    }

    float4 res;
    res.x = acc.x / denom + bias4.x;
    res.y = acc.y / denom + bias4.y;
    res.z = acc.z / denom + bias4.z;
    res.w = acc.w / denom + bias4.w;
    if (ACT == 0) {                            // ELU
        res.x = res.x > 0.f ? res.x : expm1f(res.x);
        res.y = res.y > 0.f ? res.y : expm1f(res.y);
        res.z = res.z > 0.f ? res.z : expm1f(res.z);
        res.w = res.w > 0.f ? res.w : expm1f(res.w);
    } else {                                   // softplus + 1e-4
        res.x = fmaxf(res.x, 0.f) + log1pf(expf(-fabsf(res.x))) + 1e-4f;
        res.y = fmaxf(res.y, 0.f) + log1pf(expf(-fabsf(res.y))) + 1e-4f;
        res.z = fmaxf(res.z, 0.f) + log1pf(expf(-fabsf(res.z))) + 1e-4f;
        res.w = fmaxf(res.w, 0.f) + log1pf(expf(-fabsf(res.w))) + 1e-4f;
    }
    if (g == 0)
        *(float4*)(out + (size_t)node * D + 4 * t) = res;
}

// ---------------------------------------------------------------------------
extern "C" void kernel_launch(void* const* d_in, const int* in_sizes, int n_in,
                              void* d_out, int out_size, void* d_ws, size_t ws_size,
                              hipStream_t stream)
{
    const float* x     = (const float*)d_in[0];
    const int*   ei    = (const int*)d_in[1];     // (2, E) int32
    const float* ew    = (const float*)d_in[2];
    const float* Wl1   = (const float*)d_in[3];
    const float* bl1   = (const float*)d_in[4];
    const float* Wr1   = (const float*)d_in[5];
    const float* br1   = (const float*)d_in[6];
    const float* We1   = (const float*)d_in[7];
    const float* att1  = (const float*)d_in[8];
    const float* bias1 = (const float*)d_in[9];
    const float* Wl2   = (const float*)d_in[10];
    const float* bl2   = (const float*)d_in[11];
    const float* Wr2   = (const float*)d_in[12];
    const float* br2   = (const float*)d_in[13];
    const float* We2   = (const float*)d_in[14];
    const float* att2  = (const float*)d_in[15];
    const float* bias2 = (const float*)d_in[16];
    float* out = (float*)d_out;

    const int n = in_sizes[0] / 128;
    const int E = in_sizes[2];
    const int NB = (n + 255) / 256;

    char* wp = (char*)d_ws;
    auto carve = [&](size_t bytes) -> void* {
        void* p = (void*)wp;
        wp += (bytes + 255) & ~(size_t)255;
        return p;
    };
    int*   cnt       = (int*)  carve((size_t)n * 4);
    int*   row_off   = (int*)  carve((size_t)(n + 1) * 4);
    int*   cursor    = (int*)  carve((size_t)n * 4);
    int*   bsums     = (int*)  carve((size_t)256 * 4);
    int2*  slot      = (int2*) carve((size_t)E * 8);
    float* xl1       = (float*)carve((size_t)n * 64 * 4);
    float* xr1       = (float*)carve((size_t)n * 64 * 4);
    float* hbuf      = (float*)carve((size_t)n * 64 * 4);
    float* xl2       = (float*)carve((size_t)n * 32 * 4);
    float* xr2       = (float*)carve((size_t)n * 32 * 4);

    hipMemsetAsync(cnt, 0, (size_t)n * 4, stream);

    deg_kernel    <<<(E + 255) / 256, 256, 0, stream>>>(ei, cnt, E);
    scan_p1       <<<NB, 256, 0, stream>>>(cnt, bsums, n);
    scan_p2       <<<1, 256, 0, stream>>>(bsums, NB);
    scan_p3       <<<NB, 256, 0, stream>>>(cnt, bsums, row_off, cursor, n);
    scatter_kernel<<<(E + 255) / 256, 256, 0, stream>>>(ei, ew, cursor, slot, E);

    // layer 1
    gemm_xw<128, 128><<<(n + 127) / 128, 256, 0, stream>>>(x, Wl1, Wr1, bl1, br1, xl1, xr1, n);
    edge_attn<64, 0><<<(n + 3) / 4, 256, 0, stream>>>(xl1, xr1, We1, att1, bias1,
                                                      row_off, slot, hbuf, n);
    // layer 2
    gemm_xw<64, 64><<<(n + 127) / 128, 256, 0, stream>>>(hbuf, Wl2, Wr2, bl2, br2, xl2, xr2, n);
    edge_attn<32, 1><<<(n + 3) / 4, 256, 0, stream>>>(xl2, xr2, We2, att2, bias2,
                                                      row_off, slot, out, n);
}

// Round 6
// 299.429 us; speedup vs baseline: 2.2224x; 1.1151x over previous
//
#include <hip/hip_runtime.h>
#include <math.h>

// ---------------------------------------------------------------------------
// DPP-based add: x += x[lane ^ pattern], pure VALU (no ds_bpermute latency).
// quad_perm 0xB1 = xor1, 0x4E = xor2, 0x141 = row_half_mirror (xor7),
// 0x140 = row_mirror (xor15). {1,2,7} spans 8 lanes; {1,2,7,15} spans 16.
// ---------------------------------------------------------------------------
template<int CTRL>
__device__ __forceinline__ float dpp_addf(float x)
{
    int y = __builtin_amdgcn_update_dpp(0, __float_as_int(x), CTRL, 0xf, 0xf, true);
    return x + __int_as_float(y);
}

template<int LPE>
__device__ __forceinline__ float group_reduce(float p)
{
    p = dpp_addf<0xB1>(p);     // xor 1
    p = dpp_addf<0x4E>(p);     // xor 2
    p = dpp_addf<0x141>(p);    // xor 7 (row_half_mirror) -> spans 8 lanes
    if constexpr (LPE == 16)
        p = dpp_addf<0x140>(p); // xor 15 (row_mirror) -> spans 16 lanes
    return p;
}

// ---------------------------------------------------------------------------
// Graph prep kernels
// ---------------------------------------------------------------------------

// in-degree count; also records each edge's arrival rank so the scatter pass
// needs NO atomics (slot = row_off[dst] + rank).
__global__ __launch_bounds__(256)
void deg_kernel(const int* __restrict__ ei, int* __restrict__ cnt,
                int* __restrict__ rank, int E)
{
    int e = blockIdx.x * 256 + threadIdx.x;
    if (e >= E) return;
    rank[e] = atomicAdd(&cnt[ei[E + e]], 1);
}

// --- 3-phase multi-block exclusive scan of cnt (n=50K -> 196 blocks) -------
__global__ __launch_bounds__(256)
void scan_p1(const int* __restrict__ cnt, int* __restrict__ bsums, int n)
{
    __shared__ int s[256];
    const int tid = threadIdx.x;
    int gi = blockIdx.x * 256 + tid;
    s[tid] = (gi < n) ? cnt[gi] : 0;
    __syncthreads();
    #pragma unroll
    for (int off = 128; off >= 1; off >>= 1) {
        if (tid < off) s[tid] += s[tid + off];
        __syncthreads();
    }
    if (tid == 0) bsums[blockIdx.x] = s[0];
}

__global__ __launch_bounds__(256)
void scan_p2(int* __restrict__ bsums, int nb)
{
    __shared__ int s[256];
    const int tid = threadIdx.x;
    int v = (tid < nb) ? bsums[tid] : 0;
    s[tid] = v;
    __syncthreads();
    #pragma unroll
    for (int off = 1; off < 256; off <<= 1) {
        int t = (tid >= off) ? s[tid - off] : 0;
        __syncthreads();
        s[tid] += t;
        __syncthreads();
    }
    if (tid < nb) bsums[tid] = s[tid] - v;      // exclusive
}

__global__ __launch_bounds__(256)
void scan_p3(const int* __restrict__ cnt, const int* __restrict__ bsums,
             int* __restrict__ row_off, int n)
{
    __shared__ int s[256];
    const int tid = threadIdx.x;
    int gi = blockIdx.x * 256 + tid;
    int c = (gi < n) ? cnt[gi] : 0;
    s[tid] = c;
    __syncthreads();
    #pragma unroll
    for (int off = 1; off < 256; off <<= 1) {
        int t = (tid >= off) ? s[tid - off] : 0;
        __syncthreads();
        s[tid] += t;
        __syncthreads();
    }
    if (gi < n) {
        int excl = bsums[blockIdx.x] + s[tid] - c;
        row_off[gi] = excl;
        if (gi == n - 1) row_off[n] = excl + c;   // == E
    }
}

// atomic-free scatter: slot position = row_off[dst] + rank
__global__ __launch_bounds__(256)
void scatter_kernel(const int* __restrict__ ei, const float* __restrict__ ew,
                    const int* __restrict__ row_off, const int* __restrict__ rank,
                    int2* __restrict__ slot, int E)
{
    int e = blockIdx.x * 256 + threadIdx.x;
    if (e >= E) return;
    int d = ei[E + e];
    int p = row_off[d] + rank[e];
    slot[p] = make_int2(ei[e], __float_as_int(ew[e]));
}

// ---------------------------------------------------------------------------
// Fused linear: C[m][col] = sum_k X[m][k] * W[col][k] + bias[col]
// (XOR-quad-swizzled LDS, 128x128 tile, K chunks of 32 — unchanged)
// ---------------------------------------------------------------------------
template<int N, int K>
__global__ __launch_bounds__(256, 2)
void gemm_xw(const float* __restrict__ X,
             const float* __restrict__ Wa, const float* __restrict__ Wb,
             const float* __restrict__ ba, const float* __restrict__ bb,
             float* __restrict__ OutA, float* __restrict__ OutB, int M)
{
    constexpr int NJ = N / 16;
    __shared__ float sA[128 * 32];
    __shared__ float sB[N * 32];
    const int tid = threadIdx.x;
    const int m0  = blockIdx.x * 128;
    const int rg  = tid >> 4;
    const int cg  = tid & 15;

    float acc[8][NJ];
    #pragma unroll
    for (int i = 0; i < 8; ++i)
        #pragma unroll
        for (int j = 0; j < NJ; ++j) acc[i][j] = 0.f;

    const int sr = tid >> 3;
    const int kq = tid & 7;
    const int aswz = (kq ^ (sr & 7)) << 2;

    for (int kb = 0; kb < K; kb += 32) {
        #pragma unroll
        for (int p = 0; p < 4; ++p) {
            int r = sr + 32 * p;
            float4 v = make_float4(0.f, 0.f, 0.f, 0.f);
            int gr = m0 + r;
            if (gr < M) v = *(const float4*)(X + (size_t)gr * K + kb + kq * 4);
            *(float4*)&sA[r * 32 + aswz] = v;
        }
        #pragma unroll
        for (int p = 0; p < N / 32; ++p) {
            int r = sr + 32 * p;
            const float* Wsrc = (r < N / 2) ? (Wa + (size_t)r * K)
                                            : (Wb + (size_t)(r - N / 2) * K);
            float4 v = *(const float4*)(Wsrc + kb + kq * 4);
            *(float4*)&sB[r * 32 + aswz] = v;
        }
        __syncthreads();

        #pragma unroll
        for (int q = 0; q < 8; ++q) {
            float4 a4[8], b4[NJ];
            const int sa_off = (q ^ (rg & 7)) << 2;
            const int sb_off = (q ^ (cg & 7)) << 2;
            #pragma unroll
            for (int i = 0; i < 8; ++i)
                a4[i] = *(const float4*)&sA[(rg + 16 * i) * 32 + sa_off];
            #pragma unroll
            for (int j = 0; j < NJ; ++j)
                b4[j] = *(const float4*)&sB[(cg + 16 * j) * 32 + sb_off];
            #pragma unroll
            for (int i = 0; i < 8; ++i)
                #pragma unroll
                for (int j = 0; j < NJ; ++j) {
                    acc[i][j] += a4[i].x * b4[j].x;
                    acc[i][j] += a4[i].y * b4[j].y;
                    acc[i][j] += a4[i].z * b4[j].z;
                    acc[i][j] += a4[i].w * b4[j].w;
                }
        }
        __syncthreads();
    }

    #pragma unroll
    for (int i = 0; i < 8; ++i) {
        int row = m0 + rg + 16 * i;
        if (row >= M) continue;
        #pragma unroll
        for (int j = 0; j < NJ; ++j) {
            int col = cg + 16 * j;
            if (col < N / 2) {
                OutA[(size_t)row * (N / 2) + col] = acc[i][j] + ba[col];
            } else {
                OutB[(size_t)row * (N / 2) + col - N / 2] = acc[i][j] + bb[col - N / 2];
            }
        }
    }
}

// ---------------------------------------------------------------------------
// Per-node GATv2 attention + aggregation, float4-per-lane layout.
// LPE = D/4 lanes per edge; SG = 64/LPE edges per round; 1 wave per node.
// Per-edge score reduce is pure-VALU DPP (round-5 profile showed the
// ds_bpermute butterfly was a serial ~120cyc-latency chain).
// ACT: 0 = ELU (layer 1), 1 = softplus + 1e-4 (layer 2)
// ---------------------------------------------------------------------------
template<int D, int ACT>
__global__ __launch_bounds__(256)
void edge_attn(const float* __restrict__ xl, const float* __restrict__ xr,
               const float* __restrict__ We, const float* __restrict__ att,
               const float* __restrict__ bias,
               const int* __restrict__ row_off, const int2* __restrict__ slot,
               float* __restrict__ out, int n)
{
    constexpr int LPE = D / 4;                 // lanes per edge
    constexpr int SG  = 64 / LPE;              // edges per round
    const int lane = threadIdx.x & 63;
    const int wid  = threadIdx.x >> 6;
    const int t    = lane % LPE;               // owns dims 4t..4t+3
    const int g    = lane / LPE;               // edge slot within round
    const int node = blockIdx.x * 4 + wid;
    if (node >= n) return;

    const float4 We4   = *(const float4*)(We   + 4 * t);
    const float4 att4  = *(const float4*)(att  + 4 * t);
    const float4 bias4 = *(const float4*)(bias + 4 * t);
    const float4 xr4   = *(const float4*)(xr + (size_t)node * D + 4 * t);

    const int start = row_off[node];
    const int end   = row_off[node + 1];

    float denom = 0.f, wsum = 0.f;
    float4 acc = make_float4(0.f, 0.f, 0.f, 0.f);

    auto body = [&](int2 q, float4 xv, bool active) {
        float w = __int_as_float(q.y);
        float4 v;
        v.x = xv.x + xr4.x + w * We4.x;
        v.y = xv.y + xr4.y + w * We4.y;
        v.z = xv.z + xr4.z + w * We4.z;
        v.w = xv.w + xr4.w + w * We4.w;
        float4 m;
        m.x = fmaxf(v.x, 0.2f * v.x);
        m.y = fmaxf(v.y, 0.2f * v.y);
        m.z = fmaxf(v.z, 0.2f * v.z);
        m.w = fmaxf(v.w, 0.2f * v.w);
        float p = att4.x * m.x + att4.y * m.y + att4.z * m.z + att4.w * m.w;
        p = group_reduce<LPE>(p);              // score, DPP only
        float e = active ? __expf(p) : 0.f;
        wsum  += active ? w : 0.f;
        denom += e;
        acc.x += e * xv.x;
        acc.y += e * xv.y;
        acc.z += e * xv.z;
        acc.w += e * xv.w;
    };

    int j = start;
    for (; j + 2 * SG <= end; j += 2 * SG) {   // 2 rounds in flight
        int2 qa = slot[j + g];
        int2 qb = slot[j + SG + g];
        float4 xa = *(const float4*)(xl + (size_t)qa.x * D + 4 * t);
        float4 xb = *(const float4*)(xl + (size_t)qb.x * D + 4 * t);
        body(qa, xa, true);
        body(qb, xb, true);
    }
    for (; j + SG <= end; j += SG) {
        int2 q = slot[j + g];
        float4 xv = *(const float4*)(xl + (size_t)q.x * D + 4 * t);
        body(q, xv, true);
    }
    if (j < end) {                             // predicated tail round
        int idx = min(j + g, end - 1);
        int2 q = slot[idx];
        float4 xv = *(const float4*)(xl + (size_t)q.x * D + 4 * t);
        body(q, xv, (j + g) < end);
    }

    // combine partials across the SG subgroups (once per node)
    #pragma unroll
    for (int mask = LPE; mask < 64; mask <<= 1) {
        denom += __shfl_xor(denom, mask);
        wsum  += __shfl_xor(wsum,  mask);
        acc.x += __shfl_xor(acc.x, mask);
        acc.y += __shfl_xor(acc.y, mask);
        acc.z += __shfl_xor(acc.z, mask);
        acc.w += __shfl_xor(acc.w, mask);
    }

    {   // self-loop: w = mean of incoming edge weights
        float w = wsum / (float)max(end - start, 1);
        float4 xv = *(const float4*)(xl + (size_t)node * D + 4 * t);
        float4 v;
        v.x = xv.x + xr4.x + w * We4.x;
        v.y = xv.y + xr4.y + w * We4.y;
        v.z = xv.z + xr4.z + w * We4.z;
        v.w = xv.w + xr4.w + w * We4.w;
        float4 m;
        m.x = fmaxf(v.x, 0.2f * v.x);
        m.y = fmaxf(v.y, 0.2f * v.y);
        m.z = fmaxf(v.z, 0.2f * v.z);
        m.w = fmaxf(v.w, 0.2f * v.w);
        float p = att4.x * m.x + att4.y * m.y + att4.z * m.z + att4.w * m.w;
        p = group_reduce<LPE>(p);
        float e = __expf(p);
        denom += e;
        acc.x += e * xv.x;
        acc.y += e * xv.y;
        acc.z += e * xv.z;
        acc.w += e * xv.w;
    }

    float4 res;
    res.x = acc.x / denom + bias4.x;
    res.y = acc.y / denom + bias4.y;
    res.z = acc.z / denom + bias4.z;
    res.w = acc.w / denom + bias4.w;
    if (ACT == 0) {                            // ELU
        res.x = res.x > 0.f ? res.x : expm1f(res.x);
        res.y = res.y > 0.f ? res.y : expm1f(res.y);
        res.z = res.z > 0.f ? res.z : expm1f(res.z);
        res.w = res.w > 0.f ? res.w : expm1f(res.w);
    } else {                                   // softplus + 1e-4
        res.x = fmaxf(res.x, 0.f) + log1pf(expf(-fabsf(res.x))) + 1e-4f;
        res.y = fmaxf(res.y, 0.f) + log1pf(expf(-fabsf(res.y))) + 1e-4f;
        res.z = fmaxf(res.z, 0.f) + log1pf(expf(-fabsf(res.z))) + 1e-4f;
        res.w = fmaxf(res.w, 0.f) + log1pf(expf(-fabsf(res.w))) + 1e-4f;
    }
    if (g == 0)
        *(float4*)(out + (size_t)node * D + 4 * t) = res;
}

// ---------------------------------------------------------------------------
extern "C" void kernel_launch(void* const* d_in, const int* in_sizes, int n_in,
                              void* d_out, int out_size, void* d_ws, size_t ws_size,
                              hipStream_t stream)
{
    const float* x     = (const float*)d_in[0];
    const int*   ei    = (const int*)d_in[1];     // (2, E) int32
    const float* ew    = (const float*)d_in[2];
    const float* Wl1   = (const float*)d_in[3];
    const float* bl1   = (const float*)d_in[4];
    const float* Wr1   = (const float*)d_in[5];
    const float* br1   = (const float*)d_in[6];
    const float* We1   = (const float*)d_in[7];
    const float* att1  = (const float*)d_in[8];
    const float* bias1 = (const float*)d_in[9];
    const float* Wl2   = (const float*)d_in[10];
    const float* bl2   = (const float*)d_in[11];
    const float* Wr2   = (const float*)d_in[12];
    const float* br2   = (const float*)d_in[13];
    const float* We2   = (const float*)d_in[14];
    const float* att2  = (const float*)d_in[15];
    const float* bias2 = (const float*)d_in[16];
    float* out = (float*)d_out;

    const int n = in_sizes[0] / 128;
    const int E = in_sizes[2];
    const int NB = (n + 255) / 256;

    char* wp = (char*)d_ws;
    auto carve = [&](size_t bytes) -> void* {
        void* p = (void*)wp;
        wp += (bytes + 255) & ~(size_t)255;
        return p;
    };
    int*   cnt       = (int*)  carve((size_t)n * 4);
    int*   row_off   = (int*)  carve((size_t)(n + 1) * 4);
    int*   rank      = (int*)  carve((size_t)E * 4);
    int*   bsums     = (int*)  carve((size_t)256 * 4);
    int2*  slot      = (int2*) carve((size_t)E * 8);
    float* xl1       = (float*)carve((size_t)n * 64 * 4);
    float* xr1       = (float*)carve((size_t)n * 64 * 4);
    float* hbuf      = (float*)carve((size_t)n * 64 * 4);
    float* xl2       = (float*)carve((size_t)n * 32 * 4);
    float* xr2       = (float*)carve((size_t)n * 32 * 4);

    hipMemsetAsync(cnt, 0, (size_t)n * 4, stream);

    deg_kernel    <<<(E + 255) / 256, 256, 0, stream>>>(ei, cnt, rank, E);
    scan_p1       <<<NB, 256, 0, stream>>>(cnt, bsums, n);
    scan_p2       <<<1, 256, 0, stream>>>(bsums, NB);
    scan_p3       <<<NB, 256, 0, stream>>>(cnt, bsums, row_off, n);
    scatter_kernel<<<(E + 255) / 256, 256, 0, stream>>>(ei, ew, row_off, rank, slot, E);

    // layer 1
    gemm_xw<128, 128><<<(n + 127) / 128, 256, 0, stream>>>(x, Wl1, Wr1, bl1, br1, xl1, xr1, n);
    edge_attn<64, 0><<<(n + 3) / 4, 256, 0, stream>>>(xl1, xr1, We1, att1, bias1,
                                                      row_off, slot, hbuf, n);
    // layer 2
    gemm_xw<64, 64><<<(n + 127) / 128, 256, 0, stream>>>(hbuf, Wl2, Wr2, bl2, br2, xl2, xr2, n);
    edge_attn<32, 1><<<(n + 3) / 4, 256, 0, stream>>>(xl2, xr2, We2, att2, bias2,
                                                      row_off, slot, out, n);
}